// Round 17
// baseline (86.789 us; speedup 1.0000x reference)
//
#include <hip/hip_runtime.h>

#define B_ 256
#define N_IN 1152
#define N_OUT 10
#define D_OUT 16
#define OJ 160                     // N_OUT * D_OUT
#define SN (B_*OJ)                 // 40960
#define LOG2E 1.44269504088896340736f
#define NPB 16                     // pass23: n's per block
#define NPW 4                      // pass23: n's per wave
#define NSG (N_IN/NPB)             // 72 partial groups for pass2/3
#define NPASSB (NSG*16)            // 1152 pass23 blocks
#define NPB1 32                    // pass1: n's per block (4-n K-packed, bf16-only)
#define NSG1 (N_IN/NPB1)           // 36 partial groups for pass1

typedef __attribute__((ext_vector_type(8))) short bf16x8;
typedef __attribute__((ext_vector_type(4))) float f32x4;

#define NW_ELEMS (N_IN*N_OUT*D_OUT)      // 184320 rows of 8 (W)
#define NX_ELEMS (B_*N_IN)               // 294912 rows of 8 (x)
#define NWB (NW_ELEMS/256)               // 720 W-pack blocks
#define NTILES ((N_IN/16)*(B_/16))       // 1152 x-transpose tiles

// ---- bf16 split helpers (RNE) ----
__device__ __forceinline__ unsigned short f2bf(float f) {
  unsigned u = __float_as_uint(f);
  u += 0x7fffu + ((u >> 16) & 1u);
  return (unsigned short)(u >> 16);
}
__device__ __forceinline__ float bf2f(unsigned short s) {
  return __uint_as_float(((unsigned)s) << 16);
}
__device__ __forceinline__ void split8(const float* p, bf16x8& vh, bf16x8& vl) {
  const float4 a = *(const float4*)p;
  const float4 b = *(const float4*)(p + 4);
  const float w[8] = {a.x,a.y,a.z,a.w,b.x,b.y,b.z,b.w};
#pragma unroll
  for (int e=0;e<8;e++){
    unsigned short hh = f2bf(w[e]);
    vh[e] = (short)hh;
    vl[e] = (short)f2bf(w[e] - bf2f(hh));
  }
}

// ---- DPP helpers (finish kernels) ----
template<int CTRL>
__device__ __forceinline__ float dpp_add(float xx) {
  int y = __builtin_amdgcn_mov_dpp(__float_as_int(xx), CTRL, 0xF, 0xF, false);
  return xx + __int_as_float(y);
}
__device__ __forceinline__ float quad_sum4(float xx) {
  xx = dpp_add<0xB1>(xx);   // quad_perm xor1
  xx = dpp_add<0x4E>(xx);   // quad_perm xor2
  return xx;
}

// ---- pure-VALU cross-row reduce via gfx950 permlane swaps (no DS pipe) ----
// After both steps every lane holds sum over its lane-group {l, l^16, l^32, l^48}
// with association ((r0+r1)+(r2+r3)) == the old xor16/xor32 butterfly: bit-identical.
__device__ __forceinline__ float rowpair_sum16(float t) {
  float u;
  asm("v_mov_b32 %1, %0\n\t"
      "v_permlane16_swap_b32 %1, %0"     // u(odd rows) <-> t(even rows)
      : "+v"(t), "=&v"(u));
  return t + u;                           // rows: [r0+r1, r0+r1, r2+r3, r2+r3]
}
__device__ __forceinline__ float half_sum32(float t) {
  float u;
  asm("v_mov_b32 %1, %0\n\t"
      "v_permlane32_swap_b32 %1, %0"     // u(rows 2,3) <-> t(rows 0,1)
      : "+v"(t), "=&v"(u));
  return t + u;                           // all rows: full 4-row sum
}

// ---- bijective XCD-chunk swizzle (neutral, harmless; kept) ----
__device__ __forceinline__ void sgbg_map(int bid, int& sg, int& bg) {
  const int xcd = bid & 7, q = bid >> 3;
  sg = xcd*9 + (q % 9);
  bg = q / 9;
}

// ---- pack: W linear; x via LDS-transposed 16x16 tiles -> [n][b] ----
__global__ __launch_bounds__(256) void pack_all(const float* __restrict__ W,
                                                const float* __restrict__ x,
                                                short* __restrict__ WH, short* __restrict__ WL,
                                                short* __restrict__ XH, short* __restrict__ XL) {
  const int bid = blockIdx.x, tid = threadIdx.x;
  if (bid < NWB) {
    const int t = bid*256 + tid;
    bf16x8 vh, vl; split8(W + (size_t)t*8, vh, vl);
    ((bf16x8*)WH)[t] = vh; ((bf16x8*)WL)[t] = vl;
  } else {
    __shared__ bf16x8 TH[16*17], TL[16*17];
    const int tile = bid - NWB;
    const int nt = tile >> 4, bt = tile & 15;
    const int nn = tid & 15, bb = tid >> 4;        // n fastest: coalesced reads
    bf16x8 vh, vl;
    split8(x + ((size_t)(bt*16+bb)*N_IN + nt*16+nn)*8, vh, vl);
    TH[nn*17 + bb] = vh; TL[nn*17 + bb] = vl;
    __syncthreads();
    const int bb2 = tid & 15, nn2 = tid >> 4;      // b fastest: coalesced writes
    const size_t o = (size_t)(nt*16+nn2)*B_ + bt*16 + bb2;
    ((bf16x8*)XH)[o] = TH[nn2*17 + bb2];
    ((bf16x8*)XL)[o] = TL[nn2*17 + bb2];
  }
}

// ---- pass 1 (bf16-only, 4-n K-packed): acc[o] = sum_n u_h[n] ----
__global__ __launch_bounds__(256) void caps_pass1(const short* __restrict__ WH,
                                                  const short* __restrict__ XH,
                                                  float* __restrict__ P) {
  __shared__ f32x4 red[3*640];
  const int tid = threadIdx.x, w = tid >> 6, l = tid & 63;
  const int bb = l & 15, c = l >> 4;
  const int sg = blockIdx.x, bg = blockIdx.y;
  const int b0 = bg * 16;
  const int n0 = sg*NPB1 + w*8;        // wave covers 8 n = 2 packed groups

  f32x4 acc[N_OUT];
  const f32x4 zz = {0.f,0.f,0.f,0.f};
#pragma unroll
  for (int o=0;o<N_OUT;o++) acc[o] = zz;

#pragma unroll
  for (int grp=0; grp<2; ++grp) {
    const int nb = n0 + grp*4 + c;     // this lane's K-chunk n
    const bf16x8 bfrag = *(const bf16x8*)&XH[((size_t)nb*B_ + b0 + bb)*8];
    const short* Ap = &WH[(size_t)nb*1280 + bb*8];
#pragma unroll
    for (int o=0;o<N_OUT;o++) {
      const bf16x8 afrag = *(const bf16x8*)&Ap[o*128];
      acc[o] = __builtin_amdgcn_mfma_f32_16x16x32_bf16(afrag, bfrag, acc[o], 0,0,0);
    }
  }

  if (w) {
#pragma unroll
    for (int o=0;o<N_OUT;o++) red[(w-1)*640 + o*64 + l] = acc[o];
  }
  __syncthreads();
  if (!w) {
    float* Pp = &P[(size_t)sg*SN + (size_t)(b0 + bb)*OJ + c*4];
#pragma unroll
    for (int o=0;o<N_OUT;o++) {
      acc[o] += red[o*64+l] + red[640+o*64+l] + red[1280+o*64+l];
      *(f32x4*)&Pp[o*16] = acc[o];
    }
  }
}

// K-chunk split trick (pass2/3): A chunks [WH,WL,WH,WL], B [XH,XH,XL,XL]
// => exact (Wh+Wl)(xh+xl). C layout: col=lane&15=b, row=c*4+e=j.
__global__ __launch_bounds__(256) void caps_pass23(const short* __restrict__ WH,
                                                   const short* __restrict__ WL,
                                                   const short* __restrict__ XH,
                                                   const short* __restrict__ XL,
                                                   const float* __restrict__ veff,
                                                   float* __restrict__ P) {
  __shared__ f32x4 red[3*640];
  int sg, bg; sgbg_map(blockIdx.x, sg, bg);
  const int tid = threadIdx.x, w = tid >> 6, l = tid & 63;
  const int bb = l & 15, c = l >> 4;
  const int b0 = bg * 16;
  const int n0 = sg * NPB + w * NPW;
  const short* Abase = (c & 1)  ? WL : WH;
  const short* Bbase = (c >> 1) ? XL : XH;

  f32x4 vj[N_OUT], acc[N_OUT];
  const f32x4 zz = {0.f,0.f,0.f,0.f};
  const float* vp = &veff[(size_t)(b0+bb)*OJ + c*4];
#pragma unroll
  for (int o=0;o<N_OUT;o++) { vj[o] = *(const f32x4*)&vp[o*16]; acc[o] = zz; }

  for (int nn=0; nn<NPW; ++nn) {
    const int n = n0 + nn;
    const bf16x8 bfrag = *(const bf16x8*)&Bbase[((size_t)n*B_ + b0 + bb)*8];
    const short* Ap = &Abase[(size_t)n*1280 + bb*8];
    f32x4 u[N_OUT];
#pragma unroll
    for (int o=0;o<N_OUT;o++) {
      const bf16x8 afrag = *(const bf16x8*)&Ap[o*128];
      u[o] = __builtin_amdgcn_mfma_f32_16x16x32_bf16(afrag, bfrag, zz, 0,0,0);
    }
    float ez[N_OUT], Z = 0.f;
#pragma unroll
    for (int o=0;o<N_OUT;o++) {
      float t = u[o][0]*vj[o][0] + u[o][1]*vj[o][1]
              + u[o][2]*vj[o][2] + u[o][3]*vj[o][3];
      t = rowpair_sum16(t);            // VALU permlane16_swap (was ds_swizzle)
      t = half_sum32(t);               // VALU permlane32_swap (was ds_permute)
      ez[o] = exp2f(t);                // veff already in log2 domain
      Z += ez[o];
    }
    const float invZ = __builtin_amdgcn_rcpf(Z);
#pragma unroll
    for (int o=0;o<N_OUT;o++) acc[o] += (ez[o] * invZ) * u[o];
  }

  if (w) {
#pragma unroll
    for (int o=0;o<N_OUT;o++) red[(w-1)*640 + o*64 + l] = acc[o];
  }
  __syncthreads();
  if (!w) {
    float* Pp = &P[(size_t)sg*SN + (size_t)(b0 + bb)*OJ + c*4];
#pragma unroll
    for (int o=0;o<N_OUT;o++) {
      acc[o] += red[o*64+l] + red[640+o*64+l] + red[1280+o*64+l];
      *(f32x4*)&Pp[o*16] = acc[o];
    }
  }
}

// ---- vectorized finish: f32x4 per thread (one j-quad), quad_perm reduce ----
template<int GC>
__global__ __launch_bounds__(256) void caps_finish(const float* __restrict__ P, float scale,
                                                   const float* __restrict__ vprev,
                                                   float* __restrict__ vout, float lscale) {
  const int e0 = (blockIdx.x*256 + threadIdx.x)*4;
  f32x4 t = {0.f,0.f,0.f,0.f};
#pragma unroll 8
  for (int g=0; g<GC; ++g) t += *(const f32x4*)&P[(size_t)g*SN + e0];
  t *= scale;
  const float sq = quad_sum4(t[0]*t[0] + t[1]*t[1] + t[2]*t[2] + t[3]*t[3]);
  const float k = (sq/(1.f+sq)) * rsqrtf(sq + 1e-8f) * lscale;
  f32x4 v = t * k;
  if (vprev != nullptr) v += *(const f32x4*)&vprev[e0];
  *(f32x4*)&vout[e0] = v;
}

extern "C" void kernel_launch(void* const* d_in, const int* in_sizes, int n_in,
                              void* d_out, int out_size, void* d_ws, size_t ws_size,
                              hipStream_t stream) {
  const float* x = (const float*)d_in[0];   // (256,1152,8)
  const float* W = (const float*)d_in[1];   // (1,1152,10,16,8)
  float* out = (float*)d_out;               // (256,10,16)

  float* P   = (float*)d_ws;                // 72*SN floats = 11.8 MB (pass1 uses 36)
  float* v1  = P  + (size_t)NSG*SN;         // stored * log2e
  float* v12 = v1 + SN;                     // stored * log2e
  short* WH = (short*)(v12 + SN);
  short* WL = WH + (size_t)NW_ELEMS*8;
  short* XH = WL + (size_t)NW_ELEMS*8;
  short* XL = XH + (size_t)NX_ELEMS*8;      // total ws ~= 27.5 MB

  pack_all<<<NWB + NTILES, 256, 0, stream>>>(W, x, WH, WL, XH, XL);

  // iter 1: bf16-only 4n-packed pass -> P[36] ; v1 = squash(0.1*s1)*log2e
  caps_pass1<<<dim3(NSG1,16), 256, 0, stream>>>(WH, XH, P);
  caps_finish<NSG1><<<SN/1024, 256, 0, stream>>>(P, 0.1f, nullptr, v1, LOG2E);

  // iter 2: logits = u.v1 -> P[72] ; v12 = v1 + squash(s2)*log2e
  caps_pass23<<<NPASSB, 256, 0, stream>>>(WH, WL, XH, XL, v1, P);
  caps_finish<NSG><<<SN/1024, 256, 0, stream>>>(P, 1.0f, v1, v12, LOG2E);

  // iter 3: logits = u.v12 -> P[72] ; out = squash(s3)
  caps_pass23<<<NPASSB, 256, 0, stream>>>(WH, WL, XH, XL, v12, P);
  caps_finish<NSG><<<SN/1024, 256, 0, stream>>>(P, 1.0f, nullptr, out, 1.0f);
}

// Round 18
// 79.674 us; speedup vs baseline: 1.0893x; 1.0893x over previous
//
#include <hip/hip_runtime.h>

#define B_ 256
#define N_IN 1152
#define N_OUT 10
#define D_OUT 16
#define OJ 160                     // N_OUT * D_OUT
#define SN (B_*OJ)                 // 40960
#define LOG2E 1.44269504088896340736f
#define NPB 16                     // pass23: n's per block
#define NPW 4                      // pass23: n's per wave
#define NSG (N_IN/NPB)             // 72 partial groups for pass2/3
#define NPASSB (NSG*16)            // 1152 pass23 blocks
#define NPB1 32                    // pass1: n's per block (4-n K-packed, bf16-only)
#define NSG1 (N_IN/NPB1)           // 36 partial groups for pass1

typedef __attribute__((ext_vector_type(8))) short bf16x8;
typedef __attribute__((ext_vector_type(4))) float f32x4;

#define NW_ELEMS (N_IN*N_OUT*D_OUT)      // 184320 rows of 8 (W)
#define NX_ELEMS (B_*N_IN)               // 294912 rows of 8 (x)
#define NWB (NW_ELEMS/256)               // 720 W-pack blocks
#define NTILES ((N_IN/16)*(B_/16))       // 1152 x-transpose tiles

// ---- bf16 split helpers (RNE) ----
__device__ __forceinline__ unsigned short f2bf(float f) {
  unsigned u = __float_as_uint(f);
  u += 0x7fffu + ((u >> 16) & 1u);
  return (unsigned short)(u >> 16);
}
__device__ __forceinline__ float bf2f(unsigned short s) {
  return __uint_as_float(((unsigned)s) << 16);
}
__device__ __forceinline__ void split8(const float* p, bf16x8& vh, bf16x8& vl) {
  const float4 a = *(const float4*)p;
  const float4 b = *(const float4*)(p + 4);
  const float w[8] = {a.x,a.y,a.z,a.w,b.x,b.y,b.z,b.w};
#pragma unroll
  for (int e=0;e<8;e++){
    unsigned short hh = f2bf(w[e]);
    vh[e] = (short)hh;
    vl[e] = (short)f2bf(w[e] - bf2f(hh));
  }
}

// ---- DPP helpers ----
template<int CTRL>
__device__ __forceinline__ float dpp_add(float xx) {
  int y = __builtin_amdgcn_mov_dpp(__float_as_int(xx), CTRL, 0xF, 0xF, false);
  return xx + __int_as_float(y);
}
__device__ __forceinline__ float quad_sum4(float xx) {
  xx = dpp_add<0xB1>(xx);   // quad_perm [1,0,3,2] = xor1
  xx = dpp_add<0x4E>(xx);   // quad_perm [2,3,0,1] = xor2
  return xx;                // every lane of the quad holds the 4-lane sum
}

// ---- bijective XCD-chunk swizzle (neutral but harmless; kept) ----
__device__ __forceinline__ void sgbg_map(int bid, int& sg, int& bg) {
  const int xcd = bid & 7, q = bid >> 3;
  sg = xcd*9 + (q % 9);
  bg = q / 9;
}

// ---- pack: W linear; x via LDS-transposed 16x16 tiles -> [n][b] ----
__global__ __launch_bounds__(256) void pack_all(const float* __restrict__ W,
                                                const float* __restrict__ x,
                                                short* __restrict__ WH, short* __restrict__ WL,
                                                short* __restrict__ XH, short* __restrict__ XL) {
  const int bid = blockIdx.x, tid = threadIdx.x;
  if (bid < NWB) {
    const int t = bid*256 + tid;
    bf16x8 vh, vl; split8(W + (size_t)t*8, vh, vl);
    ((bf16x8*)WH)[t] = vh; ((bf16x8*)WL)[t] = vl;
  } else {
    __shared__ bf16x8 TH[16*17], TL[16*17];
    const int tile = bid - NWB;
    const int nt = tile >> 4, bt = tile & 15;
    const int nn = tid & 15, bb = tid >> 4;        // n fastest: coalesced reads
    bf16x8 vh, vl;
    split8(x + ((size_t)(bt*16+bb)*N_IN + nt*16+nn)*8, vh, vl);
    TH[nn*17 + bb] = vh; TL[nn*17 + bb] = vl;
    __syncthreads();
    const int bb2 = tid & 15, nn2 = tid >> 4;      // b fastest: coalesced writes
    const size_t o = (size_t)(nt*16+nn2)*B_ + bt*16 + bb2;
    ((bf16x8*)XH)[o] = TH[nn2*17 + bb2];
    ((bf16x8*)XL)[o] = TL[nn2*17 + bb2];
  }
}

// ---- pass 1 (bf16-only, 4-n K-packed): acc[o] = sum_n u_h[n]  ----
// One MFMA covers 4 n's: A K-chunk c = WH[n0+c][o][j=bb][*], B K-chunk c =
// XH[n0+c][b0+bb][*]; the K=32 contraction sums over (c,i) = 4 n x 8 i.
// v1 errors (~0.5% rel) only perturb later softmax coefficients: 2nd order.
__global__ __launch_bounds__(256) void caps_pass1(const short* __restrict__ WH,
                                                  const short* __restrict__ XH,
                                                  float* __restrict__ P) {
  __shared__ f32x4 red[3*640];         // lane-contiguous 16B slots: conflict-free
  const int tid = threadIdx.x, w = tid >> 6, l = tid & 63;
  const int bb = l & 15, c = l >> 4;
  const int sg = blockIdx.x, bg = blockIdx.y;
  const int b0 = bg * 16;
  const int n0 = sg*NPB1 + w*8;        // wave covers 8 n = 2 packed groups

  f32x4 acc[N_OUT];
  const f32x4 zz = {0.f,0.f,0.f,0.f};
#pragma unroll
  for (int o=0;o<N_OUT;o++) acc[o] = zz;

#pragma unroll
  for (int grp=0; grp<2; ++grp) {
    const int nb = n0 + grp*4 + c;     // this lane's K-chunk n
    const bf16x8 bfrag = *(const bf16x8*)&XH[((size_t)nb*B_ + b0 + bb)*8];
    const short* Ap = &WH[(size_t)nb*1280 + bb*8];
#pragma unroll
    for (int o=0;o<N_OUT;o++) {
      const bf16x8 afrag = *(const bf16x8*)&Ap[o*128];
      acc[o] = __builtin_amdgcn_mfma_f32_16x16x32_bf16(afrag, bfrag, acc[o], 0,0,0);
    }
  }

  if (w) {
#pragma unroll
    for (int o=0;o<N_OUT;o++) red[(w-1)*640 + o*64 + l] = acc[o];
  }
  __syncthreads();
  if (!w) {
    float* Pp = &P[(size_t)sg*SN + (size_t)(b0 + bb)*OJ + c*4];
#pragma unroll
    for (int o=0;o<N_OUT;o++) {
      acc[o] += red[o*64+l] + red[640+o*64+l] + red[1280+o*64+l];
      *(f32x4*)&Pp[o*16] = acc[o];
    }
  }
}

// K-chunk split trick (pass2/3): A chunks [WH,WL,WH,WL], B [XH,XH,XL,XL]
// => exact (Wh+Wl)(xh+xl). C layout: col=lane&15=b, row=c*4+e=j.
__global__ __launch_bounds__(256) void caps_pass23(const short* __restrict__ WH,
                                                   const short* __restrict__ WL,
                                                   const short* __restrict__ XH,
                                                   const short* __restrict__ XL,
                                                   const float* __restrict__ veff,
                                                   float* __restrict__ P) {
  __shared__ f32x4 red[3*640];
  int sg, bg; sgbg_map(blockIdx.x, sg, bg);
  const int tid = threadIdx.x, w = tid >> 6, l = tid & 63;
  const int bb = l & 15, c = l >> 4;
  const int b0 = bg * 16;
  const int n0 = sg * NPB + w * NPW;
  const short* Abase = (c & 1)  ? WL : WH;
  const short* Bbase = (c >> 1) ? XL : XH;

  f32x4 vj[N_OUT], acc[N_OUT];
  const f32x4 zz = {0.f,0.f,0.f,0.f};
  const float* vp = &veff[(size_t)(b0+bb)*OJ + c*4];
#pragma unroll
  for (int o=0;o<N_OUT;o++) { vj[o] = *(const f32x4*)&vp[o*16]; acc[o] = zz; }

  for (int nn=0; nn<NPW; ++nn) {
    const int n = n0 + nn;
    const bf16x8 bfrag = *(const bf16x8*)&Bbase[((size_t)n*B_ + b0 + bb)*8];
    const short* Ap = &Abase[(size_t)n*1280 + bb*8];
    f32x4 u[N_OUT];
#pragma unroll
    for (int o=0;o<N_OUT;o++) {
      const bf16x8 afrag = *(const bf16x8*)&Ap[o*128];
      u[o] = __builtin_amdgcn_mfma_f32_16x16x32_bf16(afrag, bfrag, zz, 0,0,0);
    }
    float ez[N_OUT], Z = 0.f;
#pragma unroll
    for (int o=0;o<N_OUT;o++) {
      float t = u[o][0]*vj[o][0] + u[o][1]*vj[o][1]
              + u[o][2]*vj[o][2] + u[o][3]*vj[o][3];
      t += __shfl_xor(t, 16);
      t += __shfl_xor(t, 32);
      ez[o] = exp2f(t);                // veff already in log2 domain
      Z += ez[o];
    }
    const float invZ = __builtin_amdgcn_rcpf(Z);
#pragma unroll
    for (int o=0;o<N_OUT;o++) acc[o] += (ez[o] * invZ) * u[o];
  }

  if (w) {
#pragma unroll
    for (int o=0;o<N_OUT;o++) red[(w-1)*640 + o*64 + l] = acc[o];
  }
  __syncthreads();
  if (!w) {
    float* Pp = &P[(size_t)sg*SN + (size_t)(b0 + bb)*OJ + c*4];
#pragma unroll
    for (int o=0;o<N_OUT;o++) {
      acc[o] += red[o*64+l] + red[640+o*64+l] + red[1280+o*64+l];
      *(f32x4*)&Pp[o*16] = acc[o];
    }
  }
}

// ---- vectorized finish: f32x4 per thread (one j-quad), quad_perm reduce ----
// grid = SN/1024 = 40 blocks x 256 thr. Lanes 4k..4k+3 cover one (b,o) row.
template<int GC>
__global__ __launch_bounds__(256) void caps_finish(const float* __restrict__ P, float scale,
                                                   const float* __restrict__ vprev,
                                                   float* __restrict__ vout, float lscale) {
  const int e0 = (blockIdx.x*256 + threadIdx.x)*4;   // 4 consecutive elements
  f32x4 t = {0.f,0.f,0.f,0.f};
#pragma unroll 8
  for (int g=0; g<GC; ++g) t += *(const f32x4*)&P[(size_t)g*SN + e0];
  t *= scale;
  const float sq = quad_sum4(t[0]*t[0] + t[1]*t[1] + t[2]*t[2] + t[3]*t[3]);
  const float k = (sq/(1.f+sq)) * rsqrtf(sq + 1e-8f) * lscale;
  f32x4 v = t * k;
  if (vprev != nullptr) v += *(const f32x4*)&vprev[e0];
  *(f32x4*)&vout[e0] = v;
}

extern "C" void kernel_launch(void* const* d_in, const int* in_sizes, int n_in,
                              void* d_out, int out_size, void* d_ws, size_t ws_size,
                              hipStream_t stream) {
  const float* x = (const float*)d_in[0];   // (256,1152,8)
  const float* W = (const float*)d_in[1];   // (1,1152,10,16,8)
  float* out = (float*)d_out;               // (256,10,16)

  float* P   = (float*)d_ws;                // 72*SN floats = 11.8 MB (pass1 uses 36)
  float* v1  = P  + (size_t)NSG*SN;         // stored * log2e
  float* v12 = v1 + SN;                     // stored * log2e
  short* WH = (short*)(v12 + SN);
  short* WL = WH + (size_t)NW_ELEMS*8;
  short* XH = WL + (size_t)NW_ELEMS*8;
  short* XL = XH + (size_t)NX_ELEMS*8;      // total ws ~= 27.5 MB

  pack_all<<<NWB + NTILES, 256, 0, stream>>>(W, x, WH, WL, XH, XL);

  // iter 1: bf16-only 4n-packed pass -> P[36] ; v1 = squash(0.1*s1)*log2e
  caps_pass1<<<dim3(NSG1,16), 256, 0, stream>>>(WH, XH, P);
  caps_finish<NSG1><<<SN/1024, 256, 0, stream>>>(P, 0.1f, nullptr, v1, LOG2E);

  // iter 2: logits = u.v1 -> P[72] ; v12 = v1 + squash(s2)*log2e
  caps_pass23<<<NPASSB, 256, 0, stream>>>(WH, WL, XH, XL, v1, P);
  caps_finish<NSG><<<SN/1024, 256, 0, stream>>>(P, 1.0f, v1, v12, LOG2E);

  // iter 3: logits = u.v12 -> P[72] ; out = squash(s3)
  caps_pass23<<<NPASSB, 256, 0, stream>>>(WH, WL, XH, XL, v12, P);
  caps_finish<NSG><<<SN/1024, 256, 0, stream>>>(P, 1.0f, nullptr, out, 1.0f);
}